// Round 14
// baseline (172.357 us; speedup 1.0000x reference)
//
#include <hip/hip_runtime.h>

#define BATCH 4096
#define DIM   128
#define NT    32   // 4096 / 128 tiles per dimension
#define REPS  10   // measurement: K2 body looped; reps 0..8 -> scratch
// TEMP = 0.25 -> 1/T = 4; 4*log2(e):
#define EXP_SCALE 5.770780163555854f

typedef __bf16 bf16_t;
typedef __bf16 bf16x8 __attribute__((ext_vector_type(8)));
typedef float  f32x4  __attribute__((ext_vector_type(4)));

// ---------------------------------------------------------------------------
// MEASUREMENT ROUND 2: pipeline byte-identical to best-known (R8, 74.4us)
// EXCEPT K2's body runs REPS=10 times inside ONE dispatch (reps 0..8
// atomicAdd into never-read scratch; rep 9 into the real denoms -> final
// state bitwise identical). Purpose: K2 has NEVER surfaced in the
// fill-dominated top-5 (<40us cutoff) so we have no steady-state counters
// for it, yet by subtraction it costs ~15.5us INVARIANT to tile size,
// staging volume, atomic count, and occupancy (R11 probe, R13 null).
// The 10x dispatch (~155us) lands top-1 WITH counters; divide by 10.
//   - H-atomics-memory-side: WRITE_SIZE ~25MB, MfmaUtil<5, VALUBusy<15
//   - H-staging/latency:     all pipes idle, FETCH+WRITE small
//   - H-legit-compute:       VALUBusy>=40 or MfmaUtil>=20
// ---------------------------------------------------------------------------

// ---------------------------------------------------------------------------
// Kernel A: per row k, normalize emb_i[k] and emb_j[k] (fp32 math), write
// bf16 z_i, z_j, pos[k]. Blocks 0..7 zero the real denom region (32 KB).
// (Byte-identical to R8.)
// ---------------------------------------------------------------------------
__global__ __launch_bounds__(256) void normalize_kernel(
    const float* __restrict__ emb_i, const float* __restrict__ emb_j,
    bf16_t* __restrict__ zi, bf16_t* __restrict__ zj, float* __restrict__ pos,
    float* __restrict__ denoms /* rowDenom(4096) ++ colDenom(4096) */)
{
    if (blockIdx.x < 8) {
        int idx = (blockIdx.x * 256 + threadIdx.x) * 4;
        *(float4*)&denoms[idx] = make_float4(0.f, 0.f, 0.f, 0.f);
    }

    int wave = threadIdx.x >> 6;
    int lane = threadIdx.x & 63;
    int k = blockIdx.x * 4 + wave;

    const float2* ei = (const float2*)(emb_i + (size_t)k * DIM);
    const float2* ej = (const float2*)(emb_j + (size_t)k * DIM);
    float2 a = ei[lane];
    float2 b = ej[lane];

    float sii = a.x * a.x + a.y * a.y;
    float sjj = b.x * b.x + b.y * b.y;
    float sij = a.x * b.x + a.y * b.y;
#pragma unroll
    for (int m = 1; m < 64; m <<= 1) {
        sii += __shfl_xor(sii, m);
        sjj += __shfl_xor(sjj, m);
        sij += __shfl_xor(sij, m);
    }
    float inv_i = 1.0f / fmaxf(sqrtf(sii), 1e-12f);
    float inv_j = 1.0f / fmaxf(sqrtf(sjj), 1e-12f);

    struct bf16_2 { bf16_t x, y; };
    bf16_2 pi, pj;
    pi.x = (bf16_t)(a.x * inv_i);  pi.y = (bf16_t)(a.y * inv_i);
    pj.x = (bf16_t)(b.x * inv_j);  pj.y = (bf16_t)(b.y * inv_j);
    ((bf16_2*)(zi + (size_t)k * DIM))[lane] = pi;
    ((bf16_2*)(zj + (size_t)k * DIM))[lane] = pj;

    if (lane == 0) pos[k] = sij * inv_i * inv_j;
}

// ---------------------------------------------------------------------------
// Kernel B: proven R8 128x128 body, wrapped in a REPS loop. Staging is
// redone every rep (honest steady-state: LDS rewritten, barriers intact);
// the compiler cannot CSE across reps because LDS writes + atomics are
// side effects. Output pointers switch to the real denoms on the last rep.
// ---------------------------------------------------------------------------
__global__ __launch_bounds__(256) void gemm_exp_kernel(
    const bf16_t* __restrict__ zi, const bf16_t* __restrict__ zj,
    float* __restrict__ rowDenom, float* __restrict__ colDenom,
    float* __restrict__ scratchR, float* __restrict__ scratchC)
{
    __shared__ __align__(16) bf16_t zi_s[128][136];
    __shared__ __align__(16) bf16_t zj_s[128][136];
    __shared__ float colRed[4][128];

    const int tid = threadIdx.x;
    const int ti = blockIdx.x, tj = blockIdx.y;

    const int wave = tid >> 6;
    const int lane = tid & 63;
    const int l15  = lane & 15;
    const int quad = lane >> 4;

#pragma unroll 1
    for (int rep = 0; rep < REPS; ++rep) {
        float* rD = (rep == REPS - 1) ? rowDenom : scratchR;
        float* cD = (rep == REPS - 1) ? colDenom : scratchC;

        // Stage 128x128 bf16 of each matrix: 2048 16B-chunks, 8 iters.
#pragma unroll
        for (int it = 0; it < 8; ++it) {
            int c = it * 256 + tid;
            int row = c >> 4;          // 16 chunks per row
            int col = (c & 15) << 3;   // 8 bf16 per chunk
            *(uint4*)&zi_s[row][col] =
                *(const uint4*)(zi + ((size_t)(ti * 128 + row)) * DIM + col);
            *(uint4*)&zj_s[row][col] =
                *(const uint4*)(zj + ((size_t)(tj * 128 + row)) * DIM + col);
        }
        __syncthreads();

        const f32x4 vzero = {0.f, 0.f, 0.f, 0.f};
        f32x4 acc[2][8];
#pragma unroll
        for (int rt = 0; rt < 2; ++rt)
#pragma unroll
            for (int ct = 0; ct < 8; ++ct) acc[rt][ct] = vzero;

#pragma unroll
        for (int ks = 0; ks < 4; ++ks) {
            int k0 = ks * 32 + quad * 8;
            bf16x8 afrag[2], bfrag[8];
#pragma unroll
            for (int rt = 0; rt < 2; ++rt)
                afrag[rt] = *(const bf16x8*)&zi_s[(wave * 2 + rt) * 16 + l15][k0];
#pragma unroll
            for (int ct = 0; ct < 8; ++ct)
                bfrag[ct] = *(const bf16x8*)&zj_s[ct * 16 + l15][k0];
#pragma unroll
            for (int rt = 0; rt < 2; ++rt)
#pragma unroll
                for (int ct = 0; ct < 8; ++ct)
                    acc[rt][ct] = __builtin_amdgcn_mfma_f32_16x16x32_bf16(
                        afrag[rt], bfrag[ct], acc[rt][ct], 0, 0, 0);
        }

        // Epilogue: exp and partial sums.
        float rowPart[2][4] = {{0.f, 0.f, 0.f, 0.f}, {0.f, 0.f, 0.f, 0.f}};
        float colPart[8]    = {0.f, 0.f, 0.f, 0.f, 0.f, 0.f, 0.f, 0.f};
#pragma unroll
        for (int rt = 0; rt < 2; ++rt)
#pragma unroll
            for (int ct = 0; ct < 8; ++ct)
#pragma unroll
                for (int r = 0; r < 4; ++r) {
                    float e = exp2f(acc[rt][ct][r] * EXP_SCALE);
                    rowPart[rt][r] += e;   // row = (wave*2+rt)*16 + quad*4 + r
                    colPart[ct]    += e;   // col = ct*16 + l15
                }

        // Row sums: 16-lane shfl reduce -> one atomic per row per block.
#pragma unroll
        for (int rt = 0; rt < 2; ++rt)
#pragma unroll
            for (int r = 0; r < 4; ++r) {
                float v = rowPart[rt][r];
                v += __shfl_xor(v, 1);
                v += __shfl_xor(v, 2);
                v += __shfl_xor(v, 4);
                v += __shfl_xor(v, 8);
                if (l15 == 0) {
                    int grow = ti * 128 + (wave * 2 + rt) * 16 + quad * 4 + r;
                    atomicAdd(&rD[grow], v);
                }
            }

        // Col sums: quad shfl-reduce, cross-wave LDS reduce, 128 coalesced
        // atomics per block.
#pragma unroll
        for (int ct = 0; ct < 8; ++ct) {
            float v = colPart[ct];
            v += __shfl_xor(v, 16);
            v += __shfl_xor(v, 32);
            if (quad == 0) colRed[wave][ct * 16 + l15] = v;
        }
        __syncthreads();
        if (tid < 128) {
            float s = colRed[0][tid] + colRed[1][tid] + colRed[2][tid] + colRed[3][tid];
            atomicAdd(&cD[tj * 128 + tid], s);
        }
        // After this barrier-protected region no wave touches zi_s/zj_s in
        // this rep; next rep's staging may begin (disjoint LDS arrays).
    }
}

// ---------------------------------------------------------------------------
// Kernel C: 1 block x 1024 threads; 3 independent float4 loads per thread,
// 8 logf, wave shfl-reduce, 16-way LDS reduce (R8 version).
// ---------------------------------------------------------------------------
__global__ __launch_bounds__(1024) void finalize_kernel(
    const float* __restrict__ denoms, const float* __restrict__ pos,
    float* __restrict__ out)
{
    const float4* rowD4 = (const float4*)denoms;            // 1024 float4
    const float4* colD4 = (const float4*)(denoms + BATCH);  // 1024 float4
    const float4* pos4  = (const float4*)pos;               // 1024 float4

    const int tid  = threadIdx.x;
    const int lane = tid & 63;
    const int wv   = tid >> 6;

    float4 rd = rowD4[tid];
    float4 cd = colD4[tid];
    float4 p  = pos4[tid];

    float acc = logf(rd.x) + logf(rd.y) + logf(rd.z) + logf(rd.w)
              + logf(cd.x) + logf(cd.y) + logf(cd.z) + logf(cd.w)
              - 8.0f * (p.x + p.y + p.z + p.w);

#pragma unroll
    for (int m = 1; m < 64; m <<= 1) acc += __shfl_xor(acc, m);

    __shared__ float red[16];
    if (lane == 0) red[wv] = acc;
    __syncthreads();
    if (wv == 0) {
        float v = (lane < 16) ? red[lane] : 0.0f;
#pragma unroll
        for (int m = 1; m < 64; m <<= 1) v += __shfl_xor(v, m);
        if (lane == 0) out[0] = v * (1.0f / (2.0f * BATCH));
    }
}

extern "C" void kernel_launch(void* const* d_in, const int* in_sizes, int n_in,
                              void* d_out, int out_size, void* d_ws, size_t ws_size,
                              hipStream_t stream) {
    const float* emb_i = (const float*)d_in[0];
    const float* emb_j = (const float*)d_in[1];
    float* out = (float*)d_out;

    char* ws = (char*)d_ws;
    bf16_t* zi       = (bf16_t*)(ws);                 // 1 MB
    bf16_t* zj       = (bf16_t*)(ws + (1u << 20));    // 1 MB
    float*  denoms   = (float*)(ws + (2u << 20));     // 32 KB (row ++ col)
    float*  pos      = denoms + 2 * BATCH;            // 16 KB
    float*  scratchR = (float*)(ws + (4u << 20));     // 16 KB (probe sink)
    float*  scratchC = scratchR + BATCH;              // 16 KB (probe sink)

    normalize_kernel<<<BATCH / 4, 256, 0, stream>>>(emb_i, emb_j, zi, zj, pos, denoms);
    gemm_exp_kernel<<<dim3(NT, NT), 256, 0, stream>>>(zi, zj, denoms, denoms + BATCH,
                                                      scratchR, scratchC);
    finalize_kernel<<<1, 1024, 0, stream>>>(denoms, pos, out);
}

// Round 15
// 73.761 us; speedup vs baseline: 2.3367x; 2.3367x over previous
//
#include <hip/hip_runtime.h>

#define BATCH 4096
#define DIM   128
#define NT    32   // 4096 / 128 tiles per dimension
// TEMP = 0.25 -> 1/T = 4; 4*log2(e):
#define EXP_SCALE 5.770780163555854f

typedef __bf16 bf16_t;
typedef __bf16 bf16x8 __attribute__((ext_vector_type(8)));
typedef float  f32x4  __attribute__((ext_vector_type(4)));

// ---------------------------------------------------------------------------
// Kernel A: per row k, normalize emb_i[k] and emb_j[k] (fp32 math), write
// bf16 z_i, z_j, pos[k]. Blocks 0..7 zero the denom region (32 KB).
// (Byte-identical to R8.)
// ---------------------------------------------------------------------------
__global__ __launch_bounds__(256) void normalize_kernel(
    const float* __restrict__ emb_i, const float* __restrict__ emb_j,
    bf16_t* __restrict__ zi, bf16_t* __restrict__ zj, float* __restrict__ pos,
    float* __restrict__ denoms /* rowDenom(4096) ++ colDenom(4096) */)
{
    if (blockIdx.x < 8) {
        int idx = (blockIdx.x * 256 + threadIdx.x) * 4;
        *(float4*)&denoms[idx] = make_float4(0.f, 0.f, 0.f, 0.f);
    }

    int wave = threadIdx.x >> 6;
    int lane = threadIdx.x & 63;
    int k = blockIdx.x * 4 + wave;

    const float2* ei = (const float2*)(emb_i + (size_t)k * DIM);
    const float2* ej = (const float2*)(emb_j + (size_t)k * DIM);
    float2 a = ei[lane];
    float2 b = ej[lane];

    float sii = a.x * a.x + a.y * a.y;
    float sjj = b.x * b.x + b.y * b.y;
    float sij = a.x * b.x + a.y * b.y;
#pragma unroll
    for (int m = 1; m < 64; m <<= 1) {
        sii += __shfl_xor(sii, m);
        sjj += __shfl_xor(sjj, m);
        sij += __shfl_xor(sij, m);
    }
    float inv_i = 1.0f / fmaxf(sqrtf(sii), 1e-12f);
    float inv_j = 1.0f / fmaxf(sqrtf(sjj), 1e-12f);

    struct bf16_2 { bf16_t x, y; };
    bf16_2 pi, pj;
    pi.x = (bf16_t)(a.x * inv_i);  pi.y = (bf16_t)(a.y * inv_i);
    pj.x = (bf16_t)(b.x * inv_j);  pj.y = (bf16_t)(b.y * inv_j);
    ((bf16_2*)(zi + (size_t)k * DIM))[lane] = pi;
    ((bf16_2*)(zj + (size_t)k * DIM))[lane] = pj;

    if (lane == 0) pos[k] = sij * inv_i * inv_j;
}

// ---------------------------------------------------------------------------
// Kernel B: 128x128 tile per block (grid 32x32), 512 threads = 8 waves.
// R14 steady-state profile (10x loop): 12.5us/rep, VALUBusy 45.8% (top
// pipe), MfmaUtil 14.2%, HBM 3% -> the kernel is an exp/VALU-throughput
// kernel, and the VALU idles because only 8 waves/CU (2/SIMD) are
// resident (70KB LDS -> 2 blocks/CU x 4 waves). FIX: same tile, same
// LDS, but 8 waves/block in a 4x2 grid (each wave 32x64 out, acc[2][4]
// = 32 VGPR) -> 16 waves/CU = 4/SIMD. Per-thread epilogue halves and
// twice the waves interleave exp/shfl with other blocks' stage/MFMA.
// __launch_bounds__(512,4) caps VGPR at 128 -- genuinely sufficient here
// (~110 needed), unlike R0/R12's spills. Differs from failed R7: no
// extra barriers, no staging split -- only the wave decomposition.
// Atomic output path (R10: partials +18us). Padded-136 rows.
// ---------------------------------------------------------------------------
__global__ __launch_bounds__(512, 4) void gemm_exp_kernel(
    const bf16_t* __restrict__ zi, const bf16_t* __restrict__ zj,
    float* __restrict__ rowDenom, float* __restrict__ colDenom)
{
    __shared__ __align__(16) bf16_t zi_s[128][136];
    __shared__ __align__(16) bf16_t zj_s[128][136];
    __shared__ float rowRed[2][128];
    __shared__ float colRed[4][128];

    const int tid = threadIdx.x;
    const int ti = blockIdx.x, tj = blockIdx.y;

    // Stage 128x128 bf16 of each matrix: 2048 16B-chunks / matrix, 4 iters.
#pragma unroll
    for (int it = 0; it < 4; ++it) {
        int c = it * 512 + tid;
        int row = c >> 4;          // 16 chunks per row
        int col = (c & 15) << 3;   // 8 bf16 per chunk
        *(uint4*)&zi_s[row][col] =
            *(const uint4*)(zi + ((size_t)(ti * 128 + row)) * DIM + col);
        *(uint4*)&zj_s[row][col] =
            *(const uint4*)(zj + ((size_t)(tj * 128 + row)) * DIM + col);
    }
    __syncthreads();

    const int wave = tid >> 6;
    const int lane = tid & 63;
    const int l15  = lane & 15;
    const int quad = lane >> 4;
    const int wr   = wave >> 1;   // 0..3 : 32-row group
    const int wc   = wave & 1;    // 0..1 : 64-col group

    const f32x4 vzero = {0.f, 0.f, 0.f, 0.f};
    f32x4 acc[2][4];
#pragma unroll
    for (int mr = 0; mr < 2; ++mr)
#pragma unroll
        for (int nc = 0; nc < 4; ++nc) acc[mr][nc] = vzero;

#pragma unroll
    for (int ks = 0; ks < 4; ++ks) {
        int k0 = ks * 32 + quad * 8;
        bf16x8 afrag[2], bfrag[4];
#pragma unroll
        for (int mr = 0; mr < 2; ++mr)
            afrag[mr] = *(const bf16x8*)&zi_s[wr * 32 + mr * 16 + l15][k0];
#pragma unroll
        for (int nc = 0; nc < 4; ++nc)
            bfrag[nc] = *(const bf16x8*)&zj_s[wc * 64 + nc * 16 + l15][k0];
#pragma unroll
        for (int mr = 0; mr < 2; ++mr)
#pragma unroll
            for (int nc = 0; nc < 4; ++nc)
                acc[mr][nc] = __builtin_amdgcn_mfma_f32_16x16x32_bf16(
                    afrag[mr], bfrag[nc], acc[mr][nc], 0, 0, 0);
    }

    // Epilogue: exp and partial sums.
    // C/D layout: col = l15, row = quad*4 + r (within each 16x16 frag).
    float rowPart[2][4] = {{0.f, 0.f, 0.f, 0.f}, {0.f, 0.f, 0.f, 0.f}};
    float colPart[4]    = {0.f, 0.f, 0.f, 0.f};
#pragma unroll
    for (int mr = 0; mr < 2; ++mr)
#pragma unroll
        for (int nc = 0; nc < 4; ++nc)
#pragma unroll
            for (int r = 0; r < 4; ++r) {
                float e = exp2f(acc[mr][nc][r] * EXP_SCALE);
                rowPart[mr][r] += e;   // row = wr*32 + mr*16 + quad*4 + r
                colPart[nc]    += e;   // col = wc*64 + nc*16 + l15
            }

    // Row sums: 16-lane shfl completes this wave's 64 cols; cross-wave
    // (2 wc-groups) via LDS.
#pragma unroll
    for (int mr = 0; mr < 2; ++mr)
#pragma unroll
        for (int r = 0; r < 4; ++r) {
            float v = rowPart[mr][r];
            v += __shfl_xor(v, 1);
            v += __shfl_xor(v, 2);
            v += __shfl_xor(v, 4);
            v += __shfl_xor(v, 8);
            if (l15 == 0)
                rowRed[wc][wr * 32 + mr * 16 + quad * 4 + r] = v;
        }

    // Col sums: quad shfl-reduce completes this wave's 32 rows;
    // cross-wave (4 wr-groups) via LDS.
#pragma unroll
    for (int nc = 0; nc < 4; ++nc) {
        float v = colPart[nc];
        v += __shfl_xor(v, 16);
        v += __shfl_xor(v, 32);
        if (quad == 0) colRed[wr][wc * 64 + nc * 16 + l15] = v;
    }
    __syncthreads();

    if (tid < 128) {
        float rs = rowRed[0][tid] + rowRed[1][tid];
        atomicAdd(&rowDenom[ti * 128 + tid], rs);
    } else if (tid < 256) {
        int c = tid - 128;
        float cs = colRed[0][c] + colRed[1][c] + colRed[2][c] + colRed[3][c];
        atomicAdd(&colDenom[tj * 128 + c], cs);
    }
}

// ---------------------------------------------------------------------------
// Kernel C: 1 block x 1024 threads; 3 independent float4 loads per thread,
// 8 logf, wave shfl-reduce, 16-way LDS reduce (R8 version).
// ---------------------------------------------------------------------------
__global__ __launch_bounds__(1024) void finalize_kernel(
    const float* __restrict__ denoms, const float* __restrict__ pos,
    float* __restrict__ out)
{
    const float4* rowD4 = (const float4*)denoms;            // 1024 float4
    const float4* colD4 = (const float4*)(denoms + BATCH);  // 1024 float4
    const float4* pos4  = (const float4*)pos;               // 1024 float4

    const int tid  = threadIdx.x;
    const int lane = tid & 63;
    const int wv   = tid >> 6;

    float4 rd = rowD4[tid];
    float4 cd = colD4[tid];
    float4 p  = pos4[tid];

    float acc = logf(rd.x) + logf(rd.y) + logf(rd.z) + logf(rd.w)
              + logf(cd.x) + logf(cd.y) + logf(cd.z) + logf(cd.w)
              - 8.0f * (p.x + p.y + p.z + p.w);

#pragma unroll
    for (int m = 1; m < 64; m <<= 1) acc += __shfl_xor(acc, m);

    __shared__ float red[16];
    if (lane == 0) red[wv] = acc;
    __syncthreads();
    if (wv == 0) {
        float v = (lane < 16) ? red[lane] : 0.0f;
#pragma unroll
        for (int m = 1; m < 64; m <<= 1) v += __shfl_xor(v, m);
        if (lane == 0) out[0] = v * (1.0f / (2.0f * BATCH));
    }
}

extern "C" void kernel_launch(void* const* d_in, const int* in_sizes, int n_in,
                              void* d_out, int out_size, void* d_ws, size_t ws_size,
                              hipStream_t stream) {
    const float* emb_i = (const float*)d_in[0];
    const float* emb_j = (const float*)d_in[1];
    float* out = (float*)d_out;

    char* ws = (char*)d_ws;
    bf16_t* zi     = (bf16_t*)(ws);                 // 1 MB
    bf16_t* zj     = (bf16_t*)(ws + (1u << 20));    // 1 MB
    float*  denoms = (float*)(ws + (2u << 20));     // 32 KB (row ++ col)
    float*  pos    = denoms + 2 * BATCH;            // 16 KB

    normalize_kernel<<<BATCH / 4, 256, 0, stream>>>(emb_i, emb_j, zi, zj, pos, denoms);
    gemm_exp_kernel<<<dim3(NT, NT), 512, 0, stream>>>(zi, zj, denoms, denoms + BATCH);
    finalize_kernel<<<1, 1024, 0, stream>>>(denoms, pos, out);
}